// Round 5
// baseline (261.288 us; speedup 1.0000x reference)
//
#include <hip/hip_runtime.h>

// RecurrentGCN (DCRNN cell, K=1) — MFMA version, round 5.
// R4 post-mortem: prefetch+coop-weights gave 103->92us, but all pipes remain
// idle (MfmaUtil 2.7%, VALU 34%, HBM 17%) with ~2 waves/SIMD resident: the
// kernel is a serial per-tile chain (vmcnt -> ds_write -> lgkm0 -> ds_read ->
// MFMA -> exp glue, x3 round trips) with nothing to hide latency under.
// This round: PAIRED-TILE SOFTWARE PIPELINE — each wave runs TWO consecutive
// 16-node tiles (32 contiguous nodes) through shared fence points; the two
// tiles' DS/MFMA/VALU chains are independent, so each phase has 2x ILP and
// fences per node halve. Works even at 2 waves/SIMD.

#define N_NODES 500000
#define IN_DIM  16
#define HID     32
#define OUT_DIM 8
#define XH      48         // IN_DIM + HID
#define NPAIRS  15625      // N_NODES / 32 (exact)
#define WROW    72         // sW row stride in bf16 (64 k-pad + 8): 144B, bank-friendly

typedef unsigned int u32;
typedef unsigned short u16;
typedef __attribute__((ext_vector_type(8))) short bf16x8;  // 8 bf16 = 4 VGPR
typedef __attribute__((ext_vector_type(4))) float f32x4;   // MFMA 16x16 acc

static __device__ __forceinline__ float bfbits(u32 hi){ union{u32 x; float f;} t; t.x=hi; return t.f; }
static __device__ __forceinline__ float bflo(u32 u){ return bfbits(u<<16); }
static __device__ __forceinline__ float bfhi(u32 u){ return bfbits(u & 0xffff0000u); }
static __device__ __forceinline__ float bf2f(u16 s){ return bfbits(((u32)s)<<16); }
static __device__ __forceinline__ float u2f(u32 u){ union{u32 x; float f;} t; t.x=u; return t.f; }
static __device__ __forceinline__ u32 f2u(float f){ union{float f;u32 x;} t; t.f=f; return t.x; }
// packed f32->bf16 RNE, 1 instr (lo = a, hi = b)
static __device__ __forceinline__ u32 cvtpk(float a, float b){
    u32 r; asm("v_cvt_pk_bf16_f32 %0, %1, %2" : "=v"(r) : "v"(a), "v"(b)); return r;
}
static __device__ __forceinline__ u16 f2bf(float f){
    union{float f;u32 x;} t; t.f=f; u32 x=t.x;
    return (u16)((x + 0x7fffu + ((x>>16)&1u)) >> 16);      // RNE
}
static __device__ __forceinline__ float sigm(float a){
    return 1.f / (1.f + __expf(-a));   // saturates cleanly at +-inf
}
static __device__ __forceinline__ float tanh_(float a){
    float e = __expf(-2.f * fabsf(a));
    float t = (1.f - e) / (1.f + e);
    return __builtin_copysignf(t, a);
}

#define LFENCE() asm volatile("s_waitcnt lgkmcnt(0)" ::: "memory")
#define MFMA16(a,b,c) __builtin_amdgcn_mfma_f32_16x16x32_bf16(a,b,c,0,0,0)

static __device__ __forceinline__ float ldf(const void* p, int i, bool F32){
    return F32 ? ((const float*)p)[i] : bf2f(((const u16*)p)[i]);
}
// combined DConv weight: w[0][k][c] + w[1][k][c], layout [2][48][32]
static __device__ __forceinline__ float wsum(const void* wp, int k, int c, bool F32){
    int i0 = k*HID + c;
    return ldf(wp, i0, F32) + ldf(wp, XH*HID + i0, F32);
}
// stage tile: [16 rows][64 bf16 cols] = 128 B rows; XOR swizzle on 16B chunks
static __device__ __forceinline__ char* stgp(char* base, int row, int off){
    return base + row*128 + (off ^ ((row & 7) << 4));
}

__global__ __launch_bounds__(256)
void rgcn_kernel(const void* __restrict__ xp_,   // [N,16]
                 const void* __restrict__ hp_,   // [N,32]
                 const void* __restrict__ wz_, const void* __restrict__ bz_,
                 const void* __restrict__ wr_, const void* __restrict__ br_,
                 const void* __restrict__ wh_, const void* __restrict__ bh_,
                 const void* __restrict__ wl_, const void* __restrict__ bl_,
                 void* __restrict__ dout_)       // out [N,8] ++ h_new [N,32]
{
    __shared__ u16 sW[3][32*WROW];     // combined bf16 weights, [true col][k+pad]
    __shared__ u16 sStage[8][16*64];   // 2 buffers per wave (tile pair)
    __shared__ int sF32;

    const int tid = threadIdx.x;

    // ---- dtype detection (wave-parallel: f32 iff any low-half is insane bf16)
    if (tid < 64) {
        const u32* xw = (const u32*)xp_;
        int bad = 0;
#pragma unroll
        for (int q = 0; q < 2; q++) {
            float lo = bflo(xw[tid*2 + q]);
            if (!(fabsf(lo) <= 1e6f)) bad = 1;
        }
        unsigned long long m = __ballot(bad);
        if (tid == 0) sF32 = (m != 0ull) ? 1 : 0;
    }
    __syncthreads();
    const bool F32 = (sF32 != 0);

    // ---- block-cooperative weight prep: sW[m][c][k] = bf16(w[0][k][c]+w[1][k][c])
    {
        const void* wsrc[3] = { wz_, wr_, wh_ };
#pragma unroll
        for (int m = 0; m < 3; m++) {
            u32* dst = (u32*)sW[m];
            for (int o = tid; o < 32*(WROW/2); o += 256) {
                int c = o / (WROW/2), kk = o - c*(WROW/2);
                int k0 = 2*kk, k1 = 2*kk + 1;
                float v0 = (k0 < XH) ? wsum(wsrc[m], k0, c, F32) : 0.f;
                float v1 = (k1 < XH) ? wsum(wsrc[m], k1, c, F32) : 0.f;
                dst[o] = cvtpk(v0, v1);
            }
        }
    }
    __syncthreads();

    const int lane = tid & 63, wv = tid >> 6;
    const int c16 = lane & 15, g = lane >> 4;     // MFMA frag coords
    const int row4 = lane >> 2, q4 = lane & 3;    // staging coords
    char* stg = (char*)sStage[wv*2];              // tile s at +2048*s

    // ---- loop-invariant LDS pointers (tile0; tile1 = +2048 folded into offset:)
    char* pXw = stgp(stg, row4, q4*8);            // x stage write (8B)
    char* pHw = stgp(stg, row4, 32 + q4*16);      // h stage write (16B)
    char* pA0 = stgp(stg, c16, 16*g);             // A frag k 0..31 (also relu(hn))
    char* pA1 = stgp(stg, c16, 64 + 16*g);        // A frag k 32..63
    char* pPairH[4]; char* pPairR[4];
#pragma unroll
    for (int rr = 0; rr < 4; rr++) {
        int nl = g*4 + rr;
        pPairH[rr] = stgp(stg, nl, 32 + 4*c16);   // h/hr pair (cols 2c16,2c16+1)
        pPairR[rr] = stgp(stg, nl, 4*c16);        // relu(hn) pair
    }

    // zero K-pad (stage bytes 96..127 per row) in both buffers, once
    {
        uint2 z2; z2.x = 0u; z2.y = 0u;
        char* pz = stgp(stg, row4, 96 + q4*8);
        *(uint2*)pz = z2;
        *(uint2*)(pz + 2048) = z2;
    }

    // ---- biases (permuted columns: tt covers col 2*c16+tt)
    float bzv[2], brv[2], bhv[2];
#pragma unroll
    for (int tt = 0; tt < 2; tt++) {
        bzv[tt] = ldf(bz_, 2*c16 + tt, F32);
        brv[tt] = ldf(br_, 2*c16 + tt, F32);
        bhv[tt] = ldf(bh_, 2*c16 + tt, F32);
    }
    float blv = (c16 < OUT_DIM) ? ldf(bl_, c16, F32) : 0.f;

    // ---- B-fragments from LDS weight images (12 ds_read_b128 per wave)
    bf16x8 Bz[2][2], Br[2][2], Bh[2][2], Bl;
#pragma unroll
    for (int kt = 0; kt < 2; kt++) {
#pragma unroll
        for (int tt = 0; tt < 2; tt++) {
            int boff = (2*c16 + tt)*(WROW*2) + (kt*32 + g*8)*2;
            Bz[kt][tt] = *(const bf16x8*)((const char*)sW[0] + boff);
            Br[kt][tt] = *(const bf16x8*)((const char*)sW[1] + boff);
            Bh[kt][tt] = *(const bf16x8*)((const char*)sW[2] + boff);
        }
    }
    {
        union { u16 us[8]; bf16x8 v; } ul;
#pragma unroll
        for (int e = 0; e < 8; e++) {
            int k = g*8 + e;
            float v = (c16 < OUT_DIM) ? ldf(wl_, k*OUT_DIM + c16, F32) : 0.f;
            ul.us[e] = f2bf(v);
        }
        Bl = ul.v;
    }

    // global output bases
    float* outF = (float*)dout_;
    float* hnF  = outF + (size_t)N_NODES * OUT_DIM;
    u16*   outB = (u16*)dout_;
    u16*   hnB  = outB + (size_t)N_NODES * OUT_DIM;

    const int wid = blockIdx.x*4 + wv;
    const int nw  = gridDim.x*4;

    // ---- prefetch registers for the PAIR (raw bits in float lanes)
    float4 pfx[2], pfh0[2], pfh1[2];
#define PLOADPAIR(PP) do { \
        _Pragma("unroll") \
        for (int s = 0; s < 2; s++) { \
            size_t nbp = (size_t)(PP)*32 + s*16; \
            if (F32) { \
                const float* xb = (const float*)xp_ + nbp*IN_DIM; \
                pfx[s]  = *(const float4*)(xb + row4*IN_DIM + q4*4); \
                const float* hb = (const float*)hp_ + nbp*HID; \
                pfh0[s] = *(const float4*)(hb + row4*HID + q4*8); \
                pfh1[s] = *(const float4*)(hb + row4*HID + q4*8 + 4); \
            } else { \
                const u16* xb = (const u16*)xp_ + nbp*IN_DIM; \
                uint2 xv = *(const uint2*)(xb + row4*IN_DIM + q4*4); \
                pfx[s].x = u2f(xv.x); pfx[s].y = u2f(xv.y); \
                const u16* hb = (const u16*)hp_ + nbp*HID; \
                uint4 hv = *(const uint4*)(hb + row4*HID + q4*8); \
                pfh0[s].x = u2f(hv.x); pfh0[s].y = u2f(hv.y); \
                pfh0[s].z = u2f(hv.z); pfh0[s].w = u2f(hv.w); \
            } \
        } \
    } while (0)

    if (wid < NPAIRS) PLOADPAIR(wid);

    for (int p = wid; p < NPAIRS; p += nw) {
        const size_t nb = (size_t)p * 32;

        // ---- phase 1: stage BOTH tiles from prefetched regs
#pragma unroll
        for (int s = 0; s < 2; s++) {
            if (F32) {
                uint2 xp2; xp2.x = cvtpk(pfx[s].x, pfx[s].y); xp2.y = cvtpk(pfx[s].z, pfx[s].w);
                *(uint2*)(pXw + s*2048) = xp2;
                uint4 hp4; hp4.x = cvtpk(pfh0[s].x, pfh0[s].y); hp4.y = cvtpk(pfh0[s].z, pfh0[s].w);
                hp4.z = cvtpk(pfh1[s].x, pfh1[s].y); hp4.w = cvtpk(pfh1[s].z, pfh1[s].w);
                *(uint4*)(pHw + s*2048) = hp4;
            } else {
                uint2 xp2; xp2.x = f2u(pfx[s].x); xp2.y = f2u(pfx[s].y);
                *(uint2*)(pXw + s*2048) = xp2;
                uint4 hp4; hp4.x = f2u(pfh0[s].x); hp4.y = f2u(pfh0[s].y);
                hp4.z = f2u(pfh0[s].z); hp4.w = f2u(pfh0[s].w);
                *(uint4*)(pHw + s*2048) = hp4;
            }
        }
        // issue NEXT pair's global loads; consumed next iteration
        {
            int pn = p + nw;
            if (pn < NPAIRS) PLOADPAIR(pn);
        }
        LFENCE();

        // ---- phase 2: GEMM1 (z,r) for both tiles — independent chains
        bf16x8 a0[2], a1[2]; u32 hwp[2][4];
#pragma unroll
        for (int s = 0; s < 2; s++) {
            a0[s] = *(const bf16x8*)(pA0 + s*2048);
            a1[s] = *(const bf16x8*)(pA1 + s*2048);
#pragma unroll
            for (int rr = 0; rr < 4; rr++) hwp[s][rr] = *(const u32*)(pPairH[rr] + s*2048);
        }
        f32x4 accZ[2][2], accR[2][2];
#pragma unroll
        for (int s = 0; s < 2; s++) {
#pragma unroll
            for (int tt = 0; tt < 2; tt++) {
                f32x4 az; az[0]=bzv[tt]; az[1]=bzv[tt]; az[2]=bzv[tt]; az[3]=bzv[tt];
                az = MFMA16(a0[s], Bz[0][tt], az);
                az = MFMA16(a1[s], Bz[1][tt], az);
                accZ[s][tt] = az;
                f32x4 ar; ar[0]=brv[tt]; ar[1]=brv[tt]; ar[2]=brv[tt]; ar[3]=brv[tt];
                ar = MFMA16(a0[s], Br[0][tt], ar);
                ar = MFMA16(a1[s], Br[1][tt], ar);
                accR[s][tt] = ar;
            }
        }
        // glue 1 (both tiles): z saved; hr pair -> cvt_pk + b32 LDS write
        float z0a[2][4], z1a[2][4], hv0[2][4], hv1[2][4];
#pragma unroll
        for (int s = 0; s < 2; s++) {
#pragma unroll
            for (int rr = 0; rr < 4; rr++) {
                float h0 = bflo(hwp[s][rr]), h1 = bfhi(hwp[s][rr]);
                hv0[s][rr] = h0; hv1[s][rr] = h1;
                float z0 = sigm(accZ[s][0][rr]), z1 = sigm(accZ[s][1][rr]);
                z0a[s][rr] = z0; z1a[s][rr] = z1;
                float r0 = sigm(accR[s][0][rr]), r1 = sigm(accR[s][1][rr]);
                *(u32*)(pPairH[rr] + s*2048) = cvtpk(h0*r0, h1*r1);
            }
        }
        LFENCE();

        // ---- phase 3: GEMMh for both tiles; glue2 + direct hn stores
        bf16x8 b0[2], b1[2];
#pragma unroll
        for (int s = 0; s < 2; s++) {
            b0[s] = *(const bf16x8*)(pA0 + s*2048);
            b1[s] = *(const bf16x8*)(pA1 + s*2048);
        }
        f32x4 accH[2][2];
#pragma unroll
        for (int s = 0; s < 2; s++) {
#pragma unroll
            for (int tt = 0; tt < 2; tt++) {
                f32x4 ah; ah[0]=bhv[tt]; ah[1]=bhv[tt]; ah[2]=bhv[tt]; ah[3]=bhv[tt];
                ah = MFMA16(b0[s], Bh[0][tt], ah);
                ah = MFMA16(b1[s], Bh[1][tt], ah);
                accH[s][tt] = ah;
            }
        }
#pragma unroll
        for (int s = 0; s < 2; s++) {
#pragma unroll
            for (int rr = 0; rr < 4; rr++) {
                int nl = g*4 + rr;
                float t0 = tanh_(accH[s][0][rr]), t1 = tanh_(accH[s][1][rr]);
                float n0 = t0 + z0a[s][rr]*(hv0[s][rr] - t0);
                float n1 = t1 + z1a[s][rr]*(hv1[s][rr] - t1);
                *(u32*)(pPairR[rr] + s*2048) = cvtpk(fmaxf(n0, 0.f), fmaxf(n1, 0.f));
                if (F32) {
                    float2 st; st.x = n0; st.y = n1;
                    *(float2*)(hnF + (nb + s*16 + nl)*HID + 2*c16) = st;
                } else {
                    *(u32*)(hnB + (nb + s*16 + nl)*HID + 2*c16) = cvtpk(n0, n1);
                }
            }
        }
        LFENCE();

        // ---- phase 4: GEMMout both tiles; store direct from acc
        bf16x8 a3[2];
#pragma unroll
        for (int s = 0; s < 2; s++) a3[s] = *(const bf16x8*)(pA0 + s*2048);
        f32x4 accO[2];
#pragma unroll
        for (int s = 0; s < 2; s++) {
            f32x4 ao; ao[0]=blv; ao[1]=blv; ao[2]=blv; ao[3]=blv;
            accO[s] = MFMA16(a3[s], Bl, ao);
        }
        if (c16 < OUT_DIM) {
#pragma unroll
            for (int s = 0; s < 2; s++) {
                if (F32) {
#pragma unroll
                    for (int rr = 0; rr < 4; rr++)
                        outF[(nb + s*16 + g*4 + rr)*OUT_DIM + c16] = accO[s][rr];
                } else {
#pragma unroll
                    for (int rr = 0; rr < 4; rr++)
                        outB[(nb + s*16 + g*4 + rr)*OUT_DIM + c16] =
                            (u16)(cvtpk(accO[s][rr], accO[s][rr]) & 0xffffu);
                }
            }
        }
    }
#undef PLOADPAIR
}

extern "C" void kernel_launch(void* const* d_in, const int* in_sizes, int n_in,
                              void* d_out, int out_size, void* d_ws, size_t ws_size,
                              hipStream_t stream) {
    // setup_inputs() order:
    // 0 x, 1 edge_index(unused), 2 edge_weight(unused), 3 h,
    // 4 w_z, 5 b_z, 6 w_r, 7 b_r, 8 w_h, 9 b_h, 10 w_lin, 11 b_lin
    const int block = 256;     // 4 waves; each wave owns independent 32-node pairs
    const int grid  = 2048;    // 8192 waves, grid-stride over 15625 pairs
    rgcn_kernel<<<grid, block, 0, stream>>>(
        d_in[0], d_in[3], d_in[4], d_in[5], d_in[6], d_in[7],
        d_in[8], d_in[9], d_in[10], d_in[11], d_out);
}